// Round 6
// baseline (751.816 us; speedup 1.0000x reference)
//
#include <hip/hip_runtime.h>

#define BB 512
#define TT 512
#define KK 64

typedef float v2f __attribute__((ext_vector_type(2)));

__device__ __forceinline__ float frl(float v, int lane) {
    return __int_as_float(__builtin_amdgcn_readlane(__float_as_int(v), lane));
}
// 3-input max in one VOP3 (clang won't fuse fmaxf chains without nnan)
__device__ __forceinline__ float fmax3(float a, float b, float c) {
    float d;
    asm("v_max3_f32 %0, %1, %2, %3" : "=v"(d) : "v"(a), "v"(b), "v"(c));
    return d;
}

// TWO interleaved unconditional Viterbi steps (independent batches) in one
// wave. Each chain is the R1-proven 16x ds_read_b128 broadcast form; chain B's
// DS issue + tree fills chain A's ~70% stall slack (R5 diagnosis: ~560cy/step
// wall vs ~110cy issue). T-fragments are shared. Max-tree associativity keeps
// M bit-exact -> equality-match backtrace unaffected. DS ops are in-order
// within a wave -> clobber, no barrier. Stores pre-unary max M (alpha_t =
// PT + M_t reconstructible bit-exactly; no freeze select).
#define FSTEP2(PT0, PT1) do {                                                   \
    la0[lane] = alpha0;                                                         \
    la1[lane] = alpha1;                                                         \
    asm volatile("" ::: "memory");                                              \
    float A0, A1, A2, A3, B0, B1, B2, B3;                                       \
    {                                                                           \
        float4 a4 = ((float4*)la0)[0];                                          \
        v2f lo; lo.x = a4.x; lo.y = a4.y; v2f cl = lo + tcl[0];                 \
        v2f hi; hi.x = a4.z; hi.y = a4.w; v2f ch = hi + tch[0];                 \
        A0 = fmaxf(cl.x, cl.y); A1 = fmaxf(ch.x, ch.y);                         \
        a4 = ((float4*)la1)[0];                                                 \
        lo.x = a4.x; lo.y = a4.y; cl = lo + tcl[0];                             \
        hi.x = a4.z; hi.y = a4.w; ch = hi + tch[0];                             \
        B0 = fmaxf(cl.x, cl.y); B1 = fmaxf(ch.x, ch.y);                         \
        a4 = ((float4*)la0)[1];                                                 \
        lo.x = a4.x; lo.y = a4.y; cl = lo + tcl[1];                             \
        hi.x = a4.z; hi.y = a4.w; ch = hi + tch[1];                             \
        A2 = fmaxf(cl.x, cl.y); A3 = fmaxf(ch.x, ch.y);                         \
        a4 = ((float4*)la1)[1];                                                 \
        lo.x = a4.x; lo.y = a4.y; cl = lo + tcl[1];                             \
        hi.x = a4.z; hi.y = a4.w; ch = hi + tch[1];                             \
        B2 = fmaxf(cl.x, cl.y); B3 = fmaxf(ch.x, ch.y);                         \
    }                                                                           \
    _Pragma("unroll")                                                           \
    for (int c = 2; c < 16; c += 2) {                                           \
        float4 a4 = ((float4*)la0)[c];                                          \
        v2f lo; lo.x = a4.x; lo.y = a4.y; v2f cl = lo + tcl[c];                 \
        v2f hi; hi.x = a4.z; hi.y = a4.w; v2f ch = hi + tch[c];                 \
        A0 = fmax3(A0, cl.x, cl.y); A1 = fmax3(A1, ch.x, ch.y);                 \
        a4 = ((float4*)la1)[c];                                                 \
        lo.x = a4.x; lo.y = a4.y; cl = lo + tcl[c];                             \
        hi.x = a4.z; hi.y = a4.w; ch = hi + tch[c];                             \
        B0 = fmax3(B0, cl.x, cl.y); B1 = fmax3(B1, ch.x, ch.y);                 \
        a4 = ((float4*)la0)[c + 1];                                             \
        lo.x = a4.x; lo.y = a4.y; cl = lo + tcl[c + 1];                         \
        hi.x = a4.z; hi.y = a4.w; ch = hi + tch[c + 1];                         \
        A2 = fmax3(A2, cl.x, cl.y); A3 = fmax3(A3, ch.x, ch.y);                 \
        a4 = ((float4*)la1)[c + 1];                                             \
        lo.x = a4.x; lo.y = a4.y; cl = lo + tcl[c + 1];                         \
        hi.x = a4.z; hi.y = a4.w; ch = hi + tch[c + 1];                         \
        B2 = fmax3(B2, cl.x, cl.y); B3 = fmax3(B3, ch.x, ch.y);                 \
    }                                                                           \
    float M0 = fmaxf(fmax3(A0, A1, A2), A3);                                    \
    float M1 = fmaxf(fmax3(B0, B1, B2), B3);                                    \
    *hp0 = M0; hp0 += KK;                                                       \
    *hp1 = M1; hp1 += KK;                                                       \
    alpha0 = (PT0) + M0;                                                        \
    alpha1 = (PT1) + M1;                                                        \
} while (0)

// ---------------------------------------------------------------------------
// Fused, dual-chain: one wave runs batches 2g and 2g+1 end-to-end
// (forward -> count -> argmax -> backtrace), all phases interleaved.
// ---------------------------------------------------------------------------
__global__ __launch_bounds__(64, 1) void crf_fused2(const float* __restrict__ pot,
                                                    const float* __restrict__ trans,
                                                    float* __restrict__ alphaH,
                                                    int* __restrict__ out) {
    __shared__ float tT[KK][KK + 1];   // tT[j][i] = trans[i][j] (backtrace)
    __shared__ __align__(16) float la0[KK];   // alpha broadcast, chain 0
    __shared__ __align__(16) float la1[KK];   // alpha broadcast, chain 1

    const int b0 = blockIdx.x * 2;
    const int lane = threadIdx.x;
    const float* pb0 = pot + (size_t)b0 * TT * KK;
    const float* pb1 = pb0 + (size_t)TT * KK;
    float* hb0 = alphaH + (size_t)b0 * TT * KK;
    float* hb1 = hb0 + (size_t)TT * KK;
    int* ob0 = out + b0 * TT;
    int* ob1 = ob0 + TT;

    // ---- stage transposed trans for backtrace (same wave: no barrier) ----
    #pragma unroll 8
    for (int r = 0; r < KK; ++r) tT[lane][r] = trans[r * KK + lane];

    // ---- trans column 'lane' as v2f pairs; pinned; SHARED by both chains ----
    v2f tcl[16], tch[16];   // tcl[c] = rows 4c,4c+1; tch[c] = rows 4c+2,4c+3
    #pragma unroll
    for (int c = 0; c < 16; ++c) {
        v2f l2, h2;
        l2.x = trans[(4 * c + 0) * KK + lane]; l2.y = trans[(4 * c + 1) * KK + lane];
        h2.x = trans[(4 * c + 2) * KK + lane]; h2.y = trans[(4 * c + 3) * KK + lane];
        tcl[c] = l2; tch[c] = h2;
    }
    #pragma unroll
    for (int c = 0; c < 16; ++c) {
        asm volatile("" : "+v"(tcl[c]));
        asm volatile("" : "+v"(tch[c]));
    }

    // ------------------------------ forward ------------------------------
    // Unconditional (no freeze): frozen-state alpha reconstructed later from
    // Mh + pot (bit-exact). Row 0 of history := 0 so alpha_0 = pot_0 + Mh_0.
    float alpha0 = pb0[lane];
    float alpha1 = pb1[lane];
    hb0[lane] = 0.0f;
    hb1[lane] = 0.0f;
    float* hp0 = hb0 + KK + lane;
    float* hp1 = hb1 + KK + lane;

    float pf0[4], pf1[4];
    #pragma unroll
    for (int u = 0; u < 4; ++u) {
        pf0[u] = pb0[(1 + u) * KK + lane];
        pf1[u] = pb1[(1 + u) * KK + lane];
    }
    const float* lp0 = pb0 + 5 * KK + lane;
    const float* lp1 = pb1 + 5 * KK + lane;

    #pragma unroll 1
    for (int c = 0; c < 126; ++c) {          // t = 1..504; loads rows 5..508
        #pragma unroll
        for (int u = 0; u < 4; ++u) {
            FSTEP2(pf0[u], pf1[u]);
            pf0[u] = *lp0; lp0 += KK;
            pf1[u] = *lp1; lp1 += KK;
        }
    }
    float e00 = pb0[509 * KK + lane], e01 = pb0[510 * KK + lane], e02 = pb0[511 * KK + lane];
    float e10 = pb1[509 * KK + lane], e11 = pb1[510 * KK + lane], e12 = pb1[511 * KK + lane];
    FSTEP2(pf0[0], pf1[0]); FSTEP2(pf0[1], pf1[1]);   // t = 505..508
    FSTEP2(pf0[2], pf1[2]); FSTEP2(pf0[3], pf1[3]);
    FSTEP2(e00, e10); FSTEP2(e01, e11); FSTEP2(e02, e12);   // t = 509..511

    // ---- seq_len: post-forward standalone count (R1-proven; fusing it into
    // the forward loads/consumes regressed 3x in R3/R4/R5 — the compiler
    // hoists the compare's vmcnt wait into the step body) ----
    int cnt0 = 0, cnt1 = 0;
    {
        const float4* p40 = (const float4*)pb0;
        const float4* p41 = (const float4*)pb1;
        #pragma unroll 4
        for (int r = 0; r < 128; ++r) {
            float4 v = p40[lane + 64 * r];
            cnt0 += (v.x != 0.f) + (v.y != 0.f) + (v.z != 0.f) + (v.w != 0.f);
            float4 w = p41[lane + 64 * r];
            cnt1 += (w.x != 0.f) + (w.y != 0.f) + (w.z != 0.f) + (w.w != 0.f);
        }
        #pragma unroll
        for (int off = 32; off > 0; off >>= 1) {
            cnt0 += __shfl_xor(cnt0, off, 64);
            cnt1 += __shfl_xor(cnt1, off, 64);
        }
    }
    const int seqlen0 = cnt0 >> 6;   // trunc(mean) — fp32-exact per R1
    const int seqlen1 = cnt1 >> 6;

    asm volatile("s_waitcnt vmcnt(0)" ::: "memory");   // M-history visible to our loads

    // ---- final alpha: live register if no freeze, else exact reconstruct ----
    float afin0 = alpha0;
    if (seqlen0 < TT) {
        if (seqlen0 <= 1) afin0 = pb0[lane];
        else afin0 = pb0[(seqlen0 - 1) * KK + lane] + hb0[(seqlen0 - 1) * KK + lane];
    }
    float afin1 = alpha1;
    if (seqlen1 < TT) {
        if (seqlen1 <= 1) afin1 = pb1[lane];
        else afin1 = pb1[(seqlen1 - 1) * KK + lane] + hb1[(seqlen1 - 1) * KK + lane];
    }

    // ---- final argmax over alpha, both chains (first occurrence on ties) ----
    float v0 = afin0; int idx0 = lane;
    float v1 = afin1; int idx1 = lane;
    #pragma unroll
    for (int off = 1; off < 64; off <<= 1) {
        float vo0 = __shfl_xor(v0, off, 64); int io0 = __shfl_xor(idx0, off, 64);
        bool t0 = (vo0 > v0) || (vo0 == v0 && io0 < idx0);
        v0 = t0 ? vo0 : v0; idx0 = t0 ? io0 : idx0;
        float vo1 = __shfl_xor(v1, off, 64); int io1 = __shfl_xor(idx1, off, 64);
        bool t1 = (vo1 > v1) || (vo1 == v1 && io1 < idx1);
        v1 = t1 ? vo1 : v1; idx1 = t1 ? io1 : idx1;
    }
    int cur0 = idx0, cur1 = idx1;    // uniform
    int slot0 = cur0, slot1 = cur1;  // lane-63 slot survives as tag at t=511

    // ---- backtrace: EQUALITY MATCH (bit-exact), both chains interleaved ----
    // bp_t(cur) = first i with (pot[t-1][i] + Mh[t-1][i]) + T[i][cur] == Mh[t][cur].
    // All three adds replay forward's exact IEEE ops, so a match always exists
    // and first-match == first-argmax (jnp.argmax tie semantics).
    float mr0 = hb0[511 * KK + lane], mr1 = hb1[511 * KK + lane];
    float m00 = hb0[510 * KK + lane], m01 = hb0[509 * KK + lane], m02 = hb0[508 * KK + lane],
          m03 = hb0[507 * KK + lane], m04 = hb0[506 * KK + lane], m05 = hb0[505 * KK + lane],
          m06 = hb0[504 * KK + lane], m07 = hb0[503 * KK + lane];
    float q00 = pb0[510 * KK + lane], q01 = pb0[509 * KK + lane], q02 = pb0[508 * KK + lane],
          q03 = pb0[507 * KK + lane], q04 = pb0[506 * KK + lane], q05 = pb0[505 * KK + lane],
          q06 = pb0[504 * KK + lane], q07 = pb0[503 * KK + lane];
    float m10 = hb1[510 * KK + lane], m11 = hb1[509 * KK + lane], m12 = hb1[508 * KK + lane],
          m13 = hb1[507 * KK + lane], m14 = hb1[506 * KK + lane], m15 = hb1[505 * KK + lane],
          m16 = hb1[504 * KK + lane], m17 = hb1[503 * KK + lane];
    float q10 = pb1[510 * KK + lane], q11 = pb1[509 * KK + lane], q12 = pb1[508 * KK + lane],
          q13 = pb1[507 * KK + lane], q14 = pb1[506 * KK + lane], q15 = pb1[505 * KK + lane],
          q16 = pb1[504 * KK + lane], q17 = pb1[503 * KK + lane];

    auto bt2 = [&](int tt, float ma, float qa, float mb, float qb) {
        if (tt < seqlen0) {   // uniform
            float target = frl(mr0, cur0);                 // Mh0[tt][cur0]
            float cand = (qa + ma) + tT[cur0][lane];       // alpha0_{tt-1}[lane] + T[lane][cur0]
            unsigned long long mk = __ballot(cand == target);
            if (mk) cur0 = (int)__builtin_ctzll(mk);       // first i == first argmax
        }
        mr0 = ma;
        if (tt < seqlen1) {   // uniform
            float target = frl(mr1, cur1);
            float cand = (qb + mb) + tT[cur1][lane];
            unsigned long long mk = __ballot(cand == target);
            if (mk) cur1 = (int)__builtin_ctzll(mk);
        }
        mr1 = mb;
        const int tm = tt - 1;
        slot0 = ((tm & 63) == lane) ? cur0 : slot0;
        slot1 = ((tm & 63) == lane) ? cur1 : slot1;
        if ((tm & 63) == 0) { ob0[tm + lane] = slot0; ob1[tm + lane] = slot1; }
    };

    int T0 = 511;
    #pragma unroll 1
    for (int c = 0; c < 63; ++c) {
        bt2(T0 - 0, m00, q00, m10, q10); { int pi = T0 - 9;  pi = pi < 0 ? 0 : pi; m00 = hb0[pi * KK + lane]; q00 = pb0[pi * KK + lane]; m10 = hb1[pi * KK + lane]; q10 = pb1[pi * KK + lane]; }
        bt2(T0 - 1, m01, q01, m11, q11); { int pi = T0 - 10; pi = pi < 0 ? 0 : pi; m01 = hb0[pi * KK + lane]; q01 = pb0[pi * KK + lane]; m11 = hb1[pi * KK + lane]; q11 = pb1[pi * KK + lane]; }
        bt2(T0 - 2, m02, q02, m12, q12); { int pi = T0 - 11; pi = pi < 0 ? 0 : pi; m02 = hb0[pi * KK + lane]; q02 = pb0[pi * KK + lane]; m12 = hb1[pi * KK + lane]; q12 = pb1[pi * KK + lane]; }
        bt2(T0 - 3, m03, q03, m13, q13); { int pi = T0 - 12; pi = pi < 0 ? 0 : pi; m03 = hb0[pi * KK + lane]; q03 = pb0[pi * KK + lane]; m13 = hb1[pi * KK + lane]; q13 = pb1[pi * KK + lane]; }
        bt2(T0 - 4, m04, q04, m14, q14); { int pi = T0 - 13; pi = pi < 0 ? 0 : pi; m04 = hb0[pi * KK + lane]; q04 = pb0[pi * KK + lane]; m14 = hb1[pi * KK + lane]; q14 = pb1[pi * KK + lane]; }
        bt2(T0 - 5, m05, q05, m15, q15); { int pi = T0 - 14; pi = pi < 0 ? 0 : pi; m05 = hb0[pi * KK + lane]; q05 = pb0[pi * KK + lane]; m15 = hb1[pi * KK + lane]; q15 = pb1[pi * KK + lane]; }
        bt2(T0 - 6, m06, q06, m16, q16); { int pi = T0 - 15; pi = pi < 0 ? 0 : pi; m06 = hb0[pi * KK + lane]; q06 = pb0[pi * KK + lane]; m16 = hb1[pi * KK + lane]; q16 = pb1[pi * KK + lane]; }
        bt2(T0 - 7, m07, q07, m17, q17); { int pi = T0 - 16; pi = pi < 0 ? 0 : pi; m07 = hb0[pi * KK + lane]; q07 = pb0[pi * KK + lane]; m17 = hb1[pi * KK + lane]; q17 = pb1[pi * KK + lane]; }
        T0 -= 8;
    }
    bt2(7, m00, q00, m10, q10); bt2(6, m01, q01, m11, q11);
    bt2(5, m02, q02, m12, q12); bt2(4, m03, q03, m13, q13);
    bt2(3, m04, q04, m14, q14); bt2(2, m05, q05, m15, q15);
    bt2(1, m06, q06, m16, q16);
}

// ---------------------------------------------------------------------------
// Fallback path (proven R1 kernels) -- only if ws can't hold the history.
// ---------------------------------------------------------------------------
__global__ __launch_bounds__(256) void seqlen_kernel(const float* __restrict__ inp,
                                                     int* __restrict__ seq_lens) {
    int b = blockIdx.x;
    int tid = threadIdx.x;
    const float4* p4 = (const float4*)(inp + (size_t)b * TT * KK);
    const int n4 = TT * KK / 4;
    int cnt = 0;
    for (int idx = tid; idx < n4; idx += 256) {
        float4 v = p4[idx];
        cnt += (v.x != 0.0f) + (v.y != 0.0f) + (v.z != 0.0f) + (v.w != 0.0f);
    }
    #pragma unroll
    for (int off = 32; off > 0; off >>= 1) cnt += __shfl_down(cnt, off, 64);
    __shared__ int wsum[4];
    if ((tid & 63) == 0) wsum[tid >> 6] = cnt;
    __syncthreads();
    if (tid == 0) seq_lens[b] = (wsum[0] + wsum[1] + wsum[2] + wsum[3]) >> 6;
}

__global__ __launch_bounds__(64) void viterbi_fallback(const float* __restrict__ pot,
                                                       const float* __restrict__ trans,
                                                       const int* __restrict__ seq_lens,
                                                       int* __restrict__ out) {
    __shared__ unsigned char bp[TT][KK];
    const int b = blockIdx.x;
    const int j = threadIdx.x;

    float tc[KK];
    #pragma unroll
    for (int i = 0; i < KK; ++i) tc[i] = trans[i * KK + j];

    const float* pb = pot + (size_t)b * TT * KK;
    float alpha = pb[j];
    const int seqlen = seq_lens[b];

    for (int t = 1; t < TT; ++t) {
        float ptj = pb[t * KK + j];
        float m[4]; int am[4];
        #pragma unroll
        for (int c = 0; c < 4; ++c) {
            const int i = c * 16;
            float ai = frl(alpha, i);
            m[c] = ai + tc[i];
            am[c] = i;
        }
        #pragma unroll
        for (int q = 1; q < 16; ++q) {
            #pragma unroll
            for (int c = 0; c < 4; ++c) {
                const int i = c * 16 + q;
                float ai = frl(alpha, i);
                float s = ai + tc[i];
                bool g = s > m[c];
                m[c] = g ? s : m[c];
                am[c] = g ? i : am[c];
            }
        }
        float M = m[0]; int BI = am[0];
        #pragma unroll
        for (int c = 1; c < 4; ++c) {
            bool g = m[c] > M;
            M = g ? m[c] : M;
            BI = g ? am[c] : BI;
        }
        const bool valid = (t < seqlen);
        alpha = valid ? (ptj + M) : alpha;
        bp[t][j] = (unsigned char)(valid ? BI : j);
    }

    float v = alpha; int idx = j;
    #pragma unroll
    for (int off = 1; off < 64; off <<= 1) {
        float vo = __shfl_xor(v, off, 64);
        int io = __shfl_xor(idx, off, 64);
        bool take = (vo > v) || (vo == v && io < idx);
        v = take ? vo : v;
        idx = take ? io : idx;
    }
    __syncthreads();
    if (j == 0) {
        int* ob = out + b * TT;
        int cur = idx;
        ob[TT - 1] = cur;
        for (int p = TT - 2; p >= 0; --p) {
            cur = bp[p + 1][cur];
            ob[p] = cur;
        }
    }
}

extern "C" void kernel_launch(void* const* d_in, const int* in_sizes, int n_in,
                              void* d_out, int out_size, void* d_ws, size_t ws_size,
                              hipStream_t stream) {
    const float* inp = (const float*)d_in[0];     // [B, T, K] fp32
    const float* trans = (const float*)d_in[1];   // [K, K] fp32
    int* out = (int*)d_out;                       // [B, T] int32

    const size_t histBytes = (size_t)BB * TT * KK * sizeof(float);  // 64 MB
    if (ws_size >= histBytes) {
        float* alphaH = (float*)d_ws;
        crf_fused2<<<BB / 2, 64, 0, stream>>>(inp, trans, alphaH, out);
    } else {
        int* seq = (int*)d_ws;
        seqlen_kernel<<<BB, 256, 0, stream>>>(inp, seq);
        viterbi_fallback<<<BB, KK, 0, stream>>>(inp, trans, seq, out);
    }
}

// Round 7
// 415.274 us; speedup vs baseline: 1.8104x; 1.8104x over previous
//
#include <hip/hip_runtime.h>

#define BB 512
#define TT 512
#define KK 64

typedef float v2f __attribute__((ext_vector_type(2)));

__device__ __forceinline__ float frl(float v, int lane) {
    return __int_as_float(__builtin_amdgcn_readlane(__float_as_int(v), lane));
}
// 3-input max in one VOP3 (clang won't fuse fmaxf chains without nnan)
__device__ __forceinline__ float fmax3(float a, float b, float c) {
    float d;
    asm("v_max3_f32 %0, %1, %2, %3" : "=v"(d) : "v"(a), "v"(b), "v"(c));
    return d;
}

// One UNCONDITIONAL Viterbi step via LDS broadcast (R1-proven form: 16x
// ds_read_b128). Stores the pre-unary max M (not alpha): alpha_t = PT + M_t is
// reconstructible bit-exactly -> equality-match backtrace, no freeze select.
// DS ops are in-order within a wave -> clobber, no barrier.
#define FSTEP(PT) do {                                                          \
    la[lane] = alpha;                                                           \
    asm volatile("" ::: "memory");                                              \
    float acc0, acc1, acc2, acc3;                                               \
    {                                                                           \
        float4 a4 = ((float4*)la)[0];                                           \
        v2f lo; lo.x = a4.x; lo.y = a4.y; v2f cl = lo + tcl[0];                 \
        v2f hi; hi.x = a4.z; hi.y = a4.w; v2f ch = hi + tch[0];                 \
        acc0 = fmaxf(cl.x, cl.y); acc1 = fmaxf(ch.x, ch.y);                     \
        a4 = ((float4*)la)[1];                                                  \
        lo.x = a4.x; lo.y = a4.y; cl = lo + tcl[1];                             \
        hi.x = a4.z; hi.y = a4.w; ch = hi + tch[1];                             \
        acc2 = fmaxf(cl.x, cl.y); acc3 = fmaxf(ch.x, ch.y);                     \
    }                                                                           \
    _Pragma("unroll")                                                           \
    for (int c = 2; c < 16; c += 2) {                                           \
        float4 a4 = ((float4*)la)[c];                                           \
        v2f lo; lo.x = a4.x; lo.y = a4.y; v2f cl = lo + tcl[c];                 \
        v2f hi; hi.x = a4.z; hi.y = a4.w; v2f ch = hi + tch[c];                 \
        acc0 = fmax3(acc0, cl.x, cl.y); acc1 = fmax3(acc1, ch.x, ch.y);         \
        a4 = ((float4*)la)[c + 1];                                              \
        lo.x = a4.x; lo.y = a4.y; cl = lo + tcl[c + 1];                         \
        hi.x = a4.z; hi.y = a4.w; ch = hi + tch[c + 1];                         \
        acc2 = fmax3(acc2, cl.x, cl.y); acc3 = fmax3(acc3, ch.x, ch.y);         \
    }                                                                           \
    float M = fmaxf(fmax3(acc0, acc1, acc2), acc3);                             \
    *hp = M; hp += KK;                                                          \
    alpha = (PT) + M;                                                           \
} while (0)

// ---------------------------------------------------------------------------
// Fused: unconditional max-only forward (M-history to ws) -> standalone count
// (L3-warm; fusing count into forward regressed in R3/R4/R5) -> equality-match
// backtrace. One wave per batch, 1 dispatch. Prefetch depth 8 (R7): vmcnt is
// an in-order counter shared by loads and stores; depth 4 made each pf-load
// wait drain the interleaved M-history stores (store retirement on the chain).
// Depth 8 loosens the wait to ~vmcnt(14) so stores never gate it.
// ---------------------------------------------------------------------------
__global__ __launch_bounds__(64, 1) void crf_fused(const float* __restrict__ pot,
                                                   const float* __restrict__ trans,
                                                   float* __restrict__ alphaH,
                                                   int* __restrict__ out) {
    __shared__ float tT[KK][KK + 1];   // tT[j][i] = trans[i][j] (backtrace)
    __shared__ float la[KK];           // alpha broadcast buffer (uniform reads)

    const int b = blockIdx.x;
    const int lane = threadIdx.x;
    const float* pb = pot + (size_t)b * TT * KK;
    float* hb = alphaH + (size_t)b * TT * KK;
    int* ob = out + b * TT;

    // ---- stage transposed trans for backtrace (same wave: no barrier) ----
    #pragma unroll 8
    for (int r = 0; r < KK; ++r) tT[lane][r] = trans[r * KK + lane];

    // ---- trans column 'lane' as v2f pairs ----
    v2f tcl[16], tch[16];   // tcl[c] = rows 4c,4c+1; tch[c] = rows 4c+2,4c+3
    #pragma unroll
    for (int c = 0; c < 16; ++c) {
        v2f l2, h2;
        l2.x = trans[(4 * c + 0) * KK + lane]; l2.y = trans[(4 * c + 1) * KK + lane];
        h2.x = trans[(4 * c + 2) * KK + lane]; h2.y = trans[(4 * c + 3) * KK + lane];
        tcl[c] = l2; tch[c] = h2;
    }
    #pragma unroll
    for (int c = 0; c < 16; ++c) {
        asm volatile("" : "+v"(tcl[c]));
        asm volatile("" : "+v"(tch[c]));
    }

    // ------------------------------ forward ------------------------------
    // Unconditional (no freeze): frozen-state alpha reconstructed later from
    // Mh + pot (bit-exact). Row 0 of history := 0 so alpha_0 = pot_0 + Mh_0.
    float alpha = pb[lane];
    hb[lane] = 0.0f;
    float* hp = hb + KK + lane;

    float pf[8];
    #pragma unroll
    for (int u = 0; u < 8; ++u) pf[u] = pb[(1 + u) * KK + lane];
    float ee[7];
    #pragma unroll
    for (int u = 0; u < 7; ++u) ee[u] = pb[(505 + u) * KK + lane];
    const float* lp = pb + 9 * KK + lane;

    #pragma unroll 1
    for (int c = 0; c < 62; ++c) {          // t = 1..496; loads rows 9..504
        #pragma unroll
        for (int u = 0; u < 8; ++u) {
            FSTEP(pf[u]);
            pf[u] = *lp; lp += KK;
        }
    }
    FSTEP(pf[0]); FSTEP(pf[1]); FSTEP(pf[2]); FSTEP(pf[3]);   // t = 497..504
    FSTEP(pf[4]); FSTEP(pf[5]); FSTEP(pf[6]); FSTEP(pf[7]);
    FSTEP(ee[0]); FSTEP(ee[1]); FSTEP(ee[2]); FSTEP(ee[3]);   // t = 505..511
    FSTEP(ee[4]); FSTEP(ee[5]); FSTEP(ee[6]);

    // ---- seq_len: AFTER forward (pb is L3-warm; off the cold path) ----
    int cnt = 0;
    {
        const float4* p4 = (const float4*)pb;
        #pragma unroll 4
        for (int r = 0; r < 128; ++r) {
            float4 v = p4[lane + 64 * r];
            cnt += (v.x != 0.f) + (v.y != 0.f) + (v.z != 0.f) + (v.w != 0.f);
        }
        #pragma unroll
        for (int off = 32; off > 0; off >>= 1) cnt += __shfl_xor(cnt, off, 64);
    }
    const int seqlen = cnt >> 6;   // trunc(mean) — fp32-exact per R1

    asm volatile("s_waitcnt vmcnt(0)" ::: "memory");   // M-history visible to our loads

    // ---- final alpha: live register if no freeze, else exact reconstruct ----
    float afin = alpha;
    if (seqlen < TT) {
        if (seqlen <= 1) afin = pb[lane];
        else afin = pb[(seqlen - 1) * KK + lane] + hb[(seqlen - 1) * KK + lane];
    }

    // ---- final argmax over alpha (first occurrence on ties) ----
    float v = afin; int idx = lane;
    #pragma unroll
    for (int off = 1; off < 64; off <<= 1) {
        float vo = __shfl_xor(v, off, 64);
        int io = __shfl_xor(idx, off, 64);
        bool take = (vo > v) || (vo == v && io < idx);
        v = take ? vo : v;
        idx = take ? io : idx;
    }
    int cur = idx;          // uniform
    int slot = cur;         // lane 63 slot survives as tag at t=511

    // ---- backtrace: EQUALITY MATCH (bit-exact), no DPP umax chain ----
    // bp_t(cur) = first i with (pot[t-1][i] + Mh[t-1][i]) + T[i][cur] == Mh[t][cur].
    // All three adds replay forward's exact IEEE ops, so a match always exists
    // and first-match == first-argmax (jnp.argmax tie semantics).
    float mrow = hb[511 * KK + lane];
    float m0 = hb[510 * KK + lane], m1 = hb[509 * KK + lane], m2 = hb[508 * KK + lane],
          m3 = hb[507 * KK + lane], m4 = hb[506 * KK + lane], m5 = hb[505 * KK + lane],
          m6 = hb[504 * KK + lane], m7 = hb[503 * KK + lane];
    float p0 = pb[510 * KK + lane], p1 = pb[509 * KK + lane], p2 = pb[508 * KK + lane],
          p3 = pb[507 * KK + lane], p4 = pb[506 * KK + lane], p5 = pb[505 * KK + lane],
          p6 = pb[504 * KK + lane], p7 = pb[503 * KK + lane];

    auto bt_step = [&](int tt, float mlo, float plo) {
        if (tt < seqlen) {   // uniform
            float target = frl(mrow, cur);                 // Mh[tt][cur]
            float cand = (plo + mlo) + tT[cur][lane];      // alpha_{tt-1}[lane] + T[lane][cur]
            unsigned long long mk = __ballot(cand == target);
            if (mk) cur = (int)__builtin_ctzll(mk);        // first i == first argmax
        }
        mrow = mlo;
        const int tm = tt - 1;
        slot = ((tm & 63) == lane) ? cur : slot;
        if ((tm & 63) == 0) ob[tm + lane] = slot;
    };

    int T0 = 511;
    #pragma unroll 1
    for (int c = 0; c < 63; ++c) {
        bt_step(T0 - 0, m0, p0); { int pi = T0 - 9;  pi = pi < 0 ? 0 : pi; m0 = hb[pi * KK + lane]; p0 = pb[pi * KK + lane]; }
        bt_step(T0 - 1, m1, p1); { int pi = T0 - 10; pi = pi < 0 ? 0 : pi; m1 = hb[pi * KK + lane]; p1 = pb[pi * KK + lane]; }
        bt_step(T0 - 2, m2, p2); { int pi = T0 - 11; pi = pi < 0 ? 0 : pi; m2 = hb[pi * KK + lane]; p2 = pb[pi * KK + lane]; }
        bt_step(T0 - 3, m3, p3); { int pi = T0 - 12; pi = pi < 0 ? 0 : pi; m3 = hb[pi * KK + lane]; p3 = pb[pi * KK + lane]; }
        bt_step(T0 - 4, m4, p4); { int pi = T0 - 13; pi = pi < 0 ? 0 : pi; m4 = hb[pi * KK + lane]; p4 = pb[pi * KK + lane]; }
        bt_step(T0 - 5, m5, p5); { int pi = T0 - 14; pi = pi < 0 ? 0 : pi; m5 = hb[pi * KK + lane]; p5 = pb[pi * KK + lane]; }
        bt_step(T0 - 6, m6, p6); { int pi = T0 - 15; pi = pi < 0 ? 0 : pi; m6 = hb[pi * KK + lane]; p6 = pb[pi * KK + lane]; }
        bt_step(T0 - 7, m7, p7); { int pi = T0 - 16; pi = pi < 0 ? 0 : pi; m7 = hb[pi * KK + lane]; p7 = pb[pi * KK + lane]; }
        T0 -= 8;
    }
    bt_step(7, m0, p0); bt_step(6, m1, p1); bt_step(5, m2, p2); bt_step(4, m3, p3);
    bt_step(3, m4, p4); bt_step(2, m5, p5); bt_step(1, m6, p6);
}

// ---------------------------------------------------------------------------
// Fallback path (proven R1 kernels) -- only if ws can't hold the history.
// ---------------------------------------------------------------------------
__global__ __launch_bounds__(256) void seqlen_kernel(const float* __restrict__ inp,
                                                     int* __restrict__ seq_lens) {
    int b = blockIdx.x;
    int tid = threadIdx.x;
    const float4* p4 = (const float4*)(inp + (size_t)b * TT * KK);
    const int n4 = TT * KK / 4;
    int cnt = 0;
    for (int idx = tid; idx < n4; idx += 256) {
        float4 v = p4[idx];
        cnt += (v.x != 0.0f) + (v.y != 0.0f) + (v.z != 0.0f) + (v.w != 0.0f);
    }
    #pragma unroll
    for (int off = 32; off > 0; off >>= 1) cnt += __shfl_down(cnt, off, 64);
    __shared__ int wsum[4];
    if ((tid & 63) == 0) wsum[tid >> 6] = cnt;
    __syncthreads();
    if (tid == 0) seq_lens[b] = (wsum[0] + wsum[1] + wsum[2] + wsum[3]) >> 6;
}

__global__ __launch_bounds__(64) void viterbi_fallback(const float* __restrict__ pot,
                                                       const float* __restrict__ trans,
                                                       const int* __restrict__ seq_lens,
                                                       int* __restrict__ out) {
    __shared__ unsigned char bp[TT][KK];
    const int b = blockIdx.x;
    const int j = threadIdx.x;

    float tc[KK];
    #pragma unroll
    for (int i = 0; i < KK; ++i) tc[i] = trans[i * KK + j];

    const float* pb = pot + (size_t)b * TT * KK;
    float alpha = pb[j];
    const int seqlen = seq_lens[b];

    for (int t = 1; t < TT; ++t) {
        float ptj = pb[t * KK + j];
        float m[4]; int am[4];
        #pragma unroll
        for (int c = 0; c < 4; ++c) {
            const int i = c * 16;
            float ai = frl(alpha, i);
            m[c] = ai + tc[i];
            am[c] = i;
        }
        #pragma unroll
        for (int q = 1; q < 16; ++q) {
            #pragma unroll
            for (int c = 0; c < 4; ++c) {
                const int i = c * 16 + q;
                float ai = frl(alpha, i);
                float s = ai + tc[i];
                bool g = s > m[c];
                m[c] = g ? s : m[c];
                am[c] = g ? i : am[c];
            }
        }
        float M = m[0]; int BI = am[0];
        #pragma unroll
        for (int c = 1; c < 4; ++c) {
            bool g = m[c] > M;
            M = g ? m[c] : M;
            BI = g ? am[c] : BI;
        }
        const bool valid = (t < seqlen);
        alpha = valid ? (ptj + M) : alpha;
        bp[t][j] = (unsigned char)(valid ? BI : j);
    }

    float v = alpha; int idx = j;
    #pragma unroll
    for (int off = 1; off < 64; off <<= 1) {
        float vo = __shfl_xor(v, off, 64);
        int io = __shfl_xor(idx, off, 64);
        bool take = (vo > v) || (vo == v && io < idx);
        v = take ? vo : v;
        idx = take ? io : idx;
    }
    __syncthreads();
    if (j == 0) {
        int* ob = out + b * TT;
        int cur = idx;
        ob[TT - 1] = cur;
        for (int p = TT - 2; p >= 0; --p) {
            cur = bp[p + 1][cur];
            ob[p] = cur;
        }
    }
}

extern "C" void kernel_launch(void* const* d_in, const int* in_sizes, int n_in,
                              void* d_out, int out_size, void* d_ws, size_t ws_size,
                              hipStream_t stream) {
    const float* inp = (const float*)d_in[0];     // [B, T, K] fp32
    const float* trans = (const float*)d_in[1];   // [K, K] fp32
    int* out = (int*)d_out;                       // [B, T] int32

    const size_t histBytes = (size_t)BB * TT * KK * sizeof(float);  // 64 MB
    if (ws_size >= histBytes) {
        float* alphaH = (float*)d_ws;
        crf_fused<<<BB, 64, 0, stream>>>(inp, trans, alphaH, out);
    } else {
        int* seq = (int*)d_ws;
        seqlen_kernel<<<BB, 256, 0, stream>>>(inp, seq);
        viterbi_fallback<<<BB, KK, 0, stream>>>(inp, trans, seq, out);
    }
}

// Round 10
// 295.182 us; speedup vs baseline: 2.5470x; 1.4068x over previous
//
#include <hip/hip_runtime.h>

#define BB 512
#define TT 512
#define KK 64

typedef float v2f __attribute__((ext_vector_type(2)));
typedef int v2i __attribute__((ext_vector_type(2)));

__device__ __forceinline__ float frl(float v, int lane) {
    return __int_as_float(__builtin_amdgcn_readlane(__float_as_int(v), lane));
}
__device__ __forceinline__ v2f vmax2(v2f a, v2f b) {
    v2f r; r.x = fmaxf(a.x, b.x); r.y = fmaxf(a.y, b.y); return r;
}

// One UNCONDITIONAL Viterbi step, 2-WAY split reduction (R10 = R9 with the
// permlane done via BUILTIN, not inline asm).
// R9 failed absmax=63; the lane-mapping derivation is verified correct under
// the swap semantics hardware-validated by R2's passing kernel
// (new_D=[D.lo|S.lo], new_S=[D.hi|S.hi]), so the failure is attributed to the
// VALU<->permlane wait-state hazard: raw inline asm hides the opcode from the
// compiler's hazard recognizer, and here the producing v_max immediately
// precedes the swap (single chain, no natural spacing; R2's dual-chain version
// had spacing by luck). __builtin_amdgcn_permlane32_swap lets the compiler
// insert the required wait states. fmax(sw[0],sw[1]) is symmetric, so the
// returned pair order cannot introduce a layout bug.
// Split mechanics: lane l reads only rows rbase..rbase+31 (rbase=(l>>5)*32;
// 8x ds_read_b128, same-address broadcast within each 32-lane half), computes
// a v2f partial for column pair {l&31,(l&31)+32}, then one swap + 1 fmax
// completes the exact 64-way max for column l in lane l (same layout as R1).
// Max is exactly associative -> M bit-identical -> equality-match backtrace
// unaffected. Register discipline (R2/R6/R7 collapsed to VGPR=68 reload-hell
// when demand passed ~80): t2[32] v2f REPLACES tcl/tch (same 64 VGPR),
// candidates via scalar adds reusing a4 components, 2 accs vs R1's 4.
// Stores pre-unary max M (alpha_t = PT + M_t reconstructible bit-exactly).
// DS ops are in-order within a wave -> clobber, no barrier.
#define FSTEP(PT) do {                                                          \
    la[lane] = alpha;                                                           \
    asm volatile("" ::: "memory");                                              \
    v2f accA, accB;                                                             \
    {                                                                           \
        float4 a4 = lab[0];                                                     \
        v2f c0; c0.x = a4.x + t2[0].x; c0.y = a4.x + t2[0].y;                   \
        v2f c1; c1.x = a4.y + t2[1].x; c1.y = a4.y + t2[1].y;                   \
        v2f c2; c2.x = a4.z + t2[2].x; c2.y = a4.z + t2[2].y;                   \
        v2f c3; c3.x = a4.w + t2[3].x; c3.y = a4.w + t2[3].y;                   \
        accA = vmax2(c0, c1);                                                   \
        accB = vmax2(c2, c3);                                                   \
    }                                                                           \
    _Pragma("unroll")                                                           \
    for (int k = 1; k < 8; ++k) {                                               \
        float4 a4 = lab[k];                                                     \
        v2f c0; c0.x = a4.x + t2[4*k+0].x; c0.y = a4.x + t2[4*k+0].y;           \
        v2f c1; c1.x = a4.y + t2[4*k+1].x; c1.y = a4.y + t2[4*k+1].y;           \
        v2f c2; c2.x = a4.z + t2[4*k+2].x; c2.y = a4.z + t2[4*k+2].y;           \
        v2f c3; c3.x = a4.w + t2[4*k+3].x; c3.y = a4.w + t2[4*k+3].y;           \
        accA = vmax2(accA, vmax2(c0, c1));                                      \
        accB = vmax2(accB, vmax2(c2, c3));                                      \
    }                                                                           \
    v2f accf = vmax2(accA, accB);                                               \
    v2i sw = __builtin_amdgcn_permlane32_swap(__float_as_int(accf.x),           \
                                              __float_as_int(accf.y),           \
                                              false, false);                    \
    float M = fmaxf(__int_as_float(sw[0]), __int_as_float(sw[1]));              \
    *hp = M; hp += KK;                                                          \
    alpha = (PT) + M;                                                           \
} while (0)

// ---------------------------------------------------------------------------
// Fused: unconditional max-only forward (M-history to ws) -> standalone count
// (L3-warm; fusing count into forward regressed in R3/R4/R5) -> equality-match
// backtrace. One wave per batch, 1 dispatch. Prefetch depth 4 (R1-proven;
// depth 8 collapsed the allocator in R7).
// ---------------------------------------------------------------------------
__global__ __launch_bounds__(64, 1) void crf_fused(const float* __restrict__ pot,
                                                   const float* __restrict__ trans,
                                                   float* __restrict__ alphaH,
                                                   int* __restrict__ out) {
    __shared__ float tT[KK][KK + 1];            // tT[j][i] = trans[i][j] (backtrace)
    __shared__ __align__(16) float la[KK];      // alpha broadcast buffer

    const int b = blockIdx.x;
    const int lane = threadIdx.x;
    const float* pb = pot + (size_t)b * TT * KK;
    float* hb = alphaH + (size_t)b * TT * KK;
    int* ob = out + b * TT;

    // ---- stage transposed trans for backtrace (same wave: no barrier) ----
    #pragma unroll 8
    for (int r = 0; r < KK; ++r) tT[lane][r] = trans[r * KK + lane];

    // ---- per-lane T for the 2-way split: rows rbase..rbase+31, cols
    //      {lane&31, (lane&31)+32} as v2f. 64 VGPRs, replaces tcl/tch. ----
    const int rbase = (lane >> 5) << 5;
    const int cc = lane & 31;
    const float4* lab = (const float4*)la + ((lane >> 5) << 3);

    v2f t2[32];
    #pragma unroll
    for (int r = 0; r < 32; ++r) {
        v2f x;
        x.x = trans[(rbase + r) * KK + cc];
        x.y = trans[(rbase + r) * KK + cc + 32];
        t2[r] = x;
    }
    #pragma unroll
    for (int r = 0; r < 32; ++r) asm volatile("" : "+v"(t2[r]));

    // ------------------------------ forward ------------------------------
    // Unconditional (no freeze): frozen-state alpha reconstructed later from
    // Mh + pot (bit-exact). Row 0 of history := 0 so alpha_0 = pot_0 + Mh_0.
    float alpha = pb[lane];
    hb[lane] = 0.0f;
    float* hp = hb + KK + lane;

    float pf[4];
    #pragma unroll
    for (int u = 0; u < 4; ++u) pf[u] = pb[(1 + u) * KK + lane];
    const float* lp = pb + 5 * KK + lane;

    #pragma unroll 1
    for (int c = 0; c < 126; ++c) {          // t = 1..504; loads rows 5..508
        #pragma unroll
        for (int u = 0; u < 4; ++u) {
            FSTEP(pf[u]);
            pf[u] = *lp; lp += KK;
        }
    }
    float e0 = pb[509 * KK + lane], e1 = pb[510 * KK + lane], e2 = pb[511 * KK + lane];
    FSTEP(pf[0]); FSTEP(pf[1]); FSTEP(pf[2]); FSTEP(pf[3]);   // t = 505..508
    FSTEP(e0);    FSTEP(e1);    FSTEP(e2);                    // t = 509..511

    // ---- seq_len: AFTER forward (pb is L3-warm; off the cold path) ----
    int cnt = 0;
    {
        const float4* p4 = (const float4*)pb;
        #pragma unroll 4
        for (int r = 0; r < 128; ++r) {
            float4 v = p4[lane + 64 * r];
            cnt += (v.x != 0.f) + (v.y != 0.f) + (v.z != 0.f) + (v.w != 0.f);
        }
        #pragma unroll
        for (int off = 32; off > 0; off >>= 1) cnt += __shfl_xor(cnt, off, 64);
    }
    const int seqlen = cnt >> 6;   // trunc(mean) — fp32-exact per R1

    asm volatile("s_waitcnt vmcnt(0)" ::: "memory");   // M-history visible to our loads

    // ---- final alpha: live register if no freeze, else exact reconstruct ----
    float afin = alpha;
    if (seqlen < TT) {
        if (seqlen <= 1) afin = pb[lane];
        else afin = pb[(seqlen - 1) * KK + lane] + hb[(seqlen - 1) * KK + lane];
    }

    // ---- final argmax over alpha (first occurrence on ties) ----
    float v = afin; int idx = lane;
    #pragma unroll
    for (int off = 1; off < 64; off <<= 1) {
        float vo = __shfl_xor(v, off, 64);
        int io = __shfl_xor(idx, off, 64);
        bool take = (vo > v) || (vo == v && io < idx);
        v = take ? vo : v;
        idx = take ? io : idx;
    }
    int cur = idx;          // uniform
    int slot = cur;         // lane 63 slot survives as tag at t=511

    // ---- backtrace: EQUALITY MATCH (bit-exact), no DPP umax chain ----
    // bp_t(cur) = first i with (pot[t-1][i] + Mh[t-1][i]) + T[i][cur] == Mh[t][cur].
    // All three adds replay forward's exact IEEE ops, so a match always exists
    // and first-match == first-argmax (jnp.argmax tie semantics).
    float mrow = hb[511 * KK + lane];
    float m0 = hb[510 * KK + lane], m1 = hb[509 * KK + lane], m2 = hb[508 * KK + lane],
          m3 = hb[507 * KK + lane], m4 = hb[506 * KK + lane], m5 = hb[505 * KK + lane],
          m6 = hb[504 * KK + lane], m7 = hb[503 * KK + lane];
    float p0 = pb[510 * KK + lane], p1 = pb[509 * KK + lane], p2 = pb[508 * KK + lane],
          p3 = pb[507 * KK + lane], p4 = pb[506 * KK + lane], p5 = pb[505 * KK + lane],
          p6 = pb[504 * KK + lane], p7 = pb[503 * KK + lane];

    auto bt_step = [&](int tt, float mlo, float plo) {
        if (tt < seqlen) {   // uniform
            float target = frl(mrow, cur);                 // Mh[tt][cur]
            float cand = (plo + mlo) + tT[cur][lane];      // alpha_{tt-1}[lane] + T[lane][cur]
            unsigned long long mk = __ballot(cand == target);
            if (mk) cur = (int)__builtin_ctzll(mk);        // first i == first argmax
        }
        mrow = mlo;
        const int tm = tt - 1;
        slot = ((tm & 63) == lane) ? cur : slot;
        if ((tm & 63) == 0) ob[tm + lane] = slot;
    };

    int T0 = 511;
    #pragma unroll 1
    for (int c = 0; c < 63; ++c) {
        bt_step(T0 - 0, m0, p0); { int pi = T0 - 9;  pi = pi < 0 ? 0 : pi; m0 = hb[pi * KK + lane]; p0 = pb[pi * KK + lane]; }
        bt_step(T0 - 1, m1, p1); { int pi = T0 - 10; pi = pi < 0 ? 0 : pi; m1 = hb[pi * KK + lane]; p1 = pb[pi * KK + lane]; }
        bt_step(T0 - 2, m2, p2); { int pi = T0 - 11; pi = pi < 0 ? 0 : pi; m2 = hb[pi * KK + lane]; p2 = pb[pi * KK + lane]; }
        bt_step(T0 - 3, m3, p3); { int pi = T0 - 12; pi = pi < 0 ? 0 : pi; m3 = hb[pi * KK + lane]; p3 = pb[pi * KK + lane]; }
        bt_step(T0 - 4, m4, p4); { int pi = T0 - 13; pi = pi < 0 ? 0 : pi; m4 = hb[pi * KK + lane]; p4 = pb[pi * KK + lane]; }
        bt_step(T0 - 5, m5, p5); { int pi = T0 - 14; pi = pi < 0 ? 0 : pi; m5 = hb[pi * KK + lane]; p5 = pb[pi * KK + lane]; }
        bt_step(T0 - 6, m6, p6); { int pi = T0 - 15; pi = pi < 0 ? 0 : pi; m6 = hb[pi * KK + lane]; p6 = pb[pi * KK + lane]; }
        bt_step(T0 - 7, m7, p7); { int pi = T0 - 16; pi = pi < 0 ? 0 : pi; m7 = hb[pi * KK + lane]; p7 = pb[pi * KK + lane]; }
        T0 -= 8;
    }
    bt_step(7, m0, p0); bt_step(6, m1, p1); bt_step(5, m2, p2); bt_step(4, m3, p3);
    bt_step(3, m4, p4); bt_step(2, m5, p5); bt_step(1, m6, p6);
}

// ---------------------------------------------------------------------------
// Fallback path (proven R1 kernels) -- only if ws can't hold the history.
// ---------------------------------------------------------------------------
__global__ __launch_bounds__(256) void seqlen_kernel(const float* __restrict__ inp,
                                                     int* __restrict__ seq_lens) {
    int b = blockIdx.x;
    int tid = threadIdx.x;
    const float4* p4 = (const float4*)(inp + (size_t)b * TT * KK);
    const int n4 = TT * KK / 4;
    int cnt = 0;
    for (int idx = tid; idx < n4; idx += 256) {
        float4 v = p4[idx];
        cnt += (v.x != 0.0f) + (v.y != 0.0f) + (v.z != 0.0f) + (v.w != 0.0f);
    }
    #pragma unroll
    for (int off = 32; off > 0; off >>= 1) cnt += __shfl_down(cnt, off, 64);
    __shared__ int wsum[4];
    if ((tid & 63) == 0) wsum[tid >> 6] = cnt;
    __syncthreads();
    if (tid == 0) seq_lens[b] = (wsum[0] + wsum[1] + wsum[2] + wsum[3]) >> 6;
}

__global__ __launch_bounds__(64) void viterbi_fallback(const float* __restrict__ pot,
                                                       const float* __restrict__ trans,
                                                       const int* __restrict__ seq_lens,
                                                       int* __restrict__ out) {
    __shared__ unsigned char bp[TT][KK];
    const int b = blockIdx.x;
    const int j = threadIdx.x;

    float tc[KK];
    #pragma unroll
    for (int i = 0; i < KK; ++i) tc[i] = trans[i * KK + j];

    const float* pb = pot + (size_t)b * TT * KK;
    float alpha = pb[j];
    const int seqlen = seq_lens[b];

    for (int t = 1; t < TT; ++t) {
        float ptj = pb[t * KK + j];
        float m[4]; int am[4];
        #pragma unroll
        for (int c = 0; c < 4; ++c) {
            const int i = c * 16;
            float ai = frl(alpha, i);
            m[c] = ai + tc[i];
            am[c] = i;
        }
        #pragma unroll
        for (int q = 1; q < 16; ++q) {
            #pragma unroll
            for (int c = 0; c < 4; ++c) {
                const int i = c * 16 + q;
                float ai = frl(alpha, i);
                float s = ai + tc[i];
                bool g = s > m[c];
                m[c] = g ? s : m[c];
                am[c] = g ? i : am[c];
            }
        }
        float M = m[0]; int BI = am[0];
        #pragma unroll
        for (int c = 1; c < 4; ++c) {
            bool g = m[c] > M;
            M = g ? m[c] : M;
            BI = g ? am[c] : BI;
        }
        const bool valid = (t < seqlen);
        alpha = valid ? (ptj + M) : alpha;
        bp[t][j] = (unsigned char)(valid ? BI : j);
    }

    float v = alpha; int idx = j;
    #pragma unroll
    for (int off = 1; off < 64; off <<= 1) {
        float vo = __shfl_xor(v, off, 64);
        int io = __shfl_xor(idx, off, 64);
        bool take = (vo > v) || (vo == v && io < idx);
        v = take ? vo : v;
        idx = take ? io : idx;
    }
    __syncthreads();
    if (j == 0) {
        int* ob = out + b * TT;
        int cur = idx;
        ob[TT - 1] = cur;
        for (int p = TT - 2; p >= 0; --p) {
            cur = bp[p + 1][cur];
            ob[p] = cur;
        }
    }
}

extern "C" void kernel_launch(void* const* d_in, const int* in_sizes, int n_in,
                              void* d_out, int out_size, void* d_ws, size_t ws_size,
                              hipStream_t stream) {
    const float* inp = (const float*)d_in[0];     // [B, T, K] fp32
    const float* trans = (const float*)d_in[1];   // [K, K] fp32
    int* out = (int*)d_out;                       // [B, T] int32

    const size_t histBytes = (size_t)BB * TT * KK * sizeof(float);  // 64 MB
    if (ws_size >= histBytes) {
        float* alphaH = (float*)d_ws;
        crf_fused<<<BB, 64, 0, stream>>>(inp, trans, alphaH, out);
    } else {
        int* seq = (int*)d_ws;
        seqlen_kernel<<<BB, 256, 0, stream>>>(inp, seq);
        viterbi_fallback<<<BB, KK, 0, stream>>>(inp, trans, seq, out);
    }
}